// Round 8
// baseline (173.258 us; speedup 1.0000x reference)
//
#include <hip/hip_runtime.h>

#define SEQ    8192
#define S_TILE 180            // valid output positions per tile (192 computed - 12 shrink)
#define NROW   198            // staged input rows (192 + halo 6)
#define CS     1608           // chunk stride in halves; holds 201 rows (192 + halo + pad)
#define NTHR   256            // 4 waves, ONE image per block; wave owns 3 n-tiles
#define NREC   33             // A-records: L0:2 (tap-packed), L1:6, L2:10, L3:14, MLP:1
#define BN_HALFOFF (NREC*512) // float area offset (in halves) inside d_ws

typedef __attribute__((ext_vector_type(8))) _Float16 half8;
typedef __attribute__((ext_vector_type(4))) _Float16 half4v;
typedef __attribute__((ext_vector_type(4))) float    f32x4;

__device__ __forceinline__ int uni(int v){ return __builtin_amdgcn_readfirstlane(v); }

// Unrolled (compile-time K) bias fold: sum_ci (sum_tap W[co][ci][tap]) * t_prev[ci].
template<int K>
__device__ __forceinline__ float fold_bias(const float* __restrict__ W, int co,
    const float* __restrict__ gp, const float* __restrict__ bbp,
    const float* __restrict__ rmp, const float* __restrict__ rvp)
{
    float acc = 0.f;
#pragma unroll
    for (int ci = 0; ci < 32; ++ci) {
        float sp = gp[ci] * rsqrtf(rvp[ci] + 1e-5f);
        float tp = bbp[ci] - rmp[ci]*sp;
        float wsum = 0.f;
#pragma unroll
        for (int tap = 0; tap < K; ++tap) wsum += W[(co*32 + ci)*K + tap];
        acc += wsum * tp;
    }
    return acc;
}

// ---------------- prep ----------------
// A-records in the 16x16x32 A-layout: lane l holds A[m=co=mh*16+(l&15)][k=(l>>4)*8+j].
//  rec 0..1  : L0 TAP-PACKED (mh=rec): k = tap*4+ci (k<12), W0 raw; k>=12 -> 0.
//  rec 2..7  : L1 (tap,mh): W1[co][ci=k'] * s0[ci]
//  rec 8..17 : L2 with s1;  rec 18..31: L3 with s2;  rec 32: MLP fw1*s3.
// Float area: [4][32]{bias', oob_const} then fb1'[16]. Stored activations are
// r = relu(z + bias'); seq-OOB positions store -t/s so folded math sees 0.
extern "C" __global__ void prep_kernel(
    const float* w0, const float* w1, const float* w2, const float* w3,
    const float* b0, const float* g0, const float* bb0, const float* rm0, const float* rv0,
    const float* b1, const float* g1, const float* bb1, const float* rm1, const float* rv1,
    const float* b2, const float* g2, const float* bb2, const float* rm2, const float* rv2,
    const float* b3, const float* g3, const float* bb3, const float* rm3, const float* rv3,
    const float* fw1, const float* fb1, _Float16* ws)
{
    const int tid = threadIdx.x;
    const int rec = blockIdx.x;
    if (rec < NREC) {
        if (tid < 64) {
            const int lane = tid;
            half8 h;
            if (rec < 2) {
                // L0 tap-packed: co = rec*16 + (lane&15), k = (lane>>4)*8+j
                int co = rec*16 + (lane & 15);
#pragma unroll
                for (int j = 0; j < 8; ++j) {
                    int k = (lane >> 4)*8 + j;
                    float wv = (k < 12) ? w0[(co*4 + (k & 3))*3 + (k >> 2)] : 0.0f;
                    h[j] = (_Float16)wv;
                }
            } else {
                const float* W; const float *gp, *rvp; int K, r2;
                if      (rec < 8)  { W = w1;  K = 3; r2 = rec - 2;  gp = g0; rvp = rv0; }
                else if (rec < 18) { W = w2;  K = 5; r2 = rec - 8;  gp = g1; rvp = rv1; }
                else if (rec < 32) { W = w3;  K = 7; r2 = rec - 18; gp = g2; rvp = rv2; }
                else               { W = fw1; K = 1; r2 = 0;        gp = g3; rvp = rv3; }
                int tap = r2 >> 1, mh = r2 & 1;
                int co  = mh*16 + (lane & 15);
                int ci0 = (lane >> 4) * 8;
#pragma unroll
                for (int j = 0; j < 8; ++j) {
                    int ci = ci0 + j;
                    float wv = W[(co*32 + ci)*K + tap];
                    wv *= gp[ci] * rsqrtf(rvp[ci] + 1e-5f);  // s_prev
                    h[j] = (_Float16)wv;
                }
            }
            *(half8*)(ws + rec*512 + lane*8) = h;
        }
    } else {
        float* fa = (float*)(ws + BN_HALFOFF);
        if (tid < 128) {
            int l = tid >> 5, co = tid & 31;
            const float *g, *bb, *rm, *rv, *bi;
            if      (l == 0) { g=g0; bb=bb0; rm=rm0; rv=rv0; bi=b0; }
            else if (l == 1) { g=g1; bb=bb1; rm=rm1; rv=rv1; bi=b1; }
            else if (l == 2) { g=g2; bb=bb2; rm=rm2; rv=rv2; bi=b2; }
            else             { g=g3; bb=bb3; rm=rm3; rv=rv3; bi=b3; }
            float s = g[co] * rsqrtf(rv[co] + 1e-5f);
            float t = bb[co] - rm[co]*s;
            float bias = bi[co];
            if      (l == 1) bias += fold_bias<3>(w1, co, g0, bb0, rm0, rv0);
            else if (l == 2) bias += fold_bias<5>(w2, co, g1, bb1, rm1, rv1);
            else if (l == 3) bias += fold_bias<7>(w3, co, g2, bb2, rm2, rv2);
            fa[(l*32 + co)*2 + 0] = bias;
            fa[(l*32 + co)*2 + 1] = -t / s;    // stored value at seq-OOB output positions
        } else if (tid < 144) {
            int hh = tid - 128;
            float acc = fb1[hh];
#pragma unroll
            for (int c = 0; c < 32; ++c) {
                float s3 = g3[c] * rsqrtf(rv3[c] + 1e-5f);
                float t3 = bb3[c] - rm3[c]*s3;
                acc += fw1[hh*32 + c] * t3;
            }
            fa[256 + hh] = acc;                // fb1'
        }
    }
}

// ---------------- shared epilogue (R0/R7-verified) ----------------
// D: col=lane&15 -> pos, row=q*4+r -> co (within m-half). r = relu(acc+bias');
// seq-OOB -> per-co const. Store half4 to chunk cb=mh*2+(q>>1).
__device__ __forceinline__ void conv_epi(
    const f32x4 (*acc)[2], const float2* __restrict__ bo,
    _Float16* outb, int s0, int doff, int ntb, int q, int n)
{
#pragma unroll
    for (int nt = 0; nt < 3; ++nt) {
        int pos = (ntb + nt)*16 + n;
        bool oob = (unsigned)(s0 + doff + pos) >= SEQ;
#pragma unroll
        for (int mh = 0; mh < 2; ++mh) {
            int co0 = mh*16 + q*4;
            half4v hv;
#pragma unroll
            for (int r = 0; r < 4; ++r) {
                float2 p = bo[co0 + r];   // x=bias' y=oob-const
                float v = fmaxf(acc[nt][mh][r] + p.x, 0.0f);
                if (oob) v = p.y;
                hv[r] = (_Float16)v;
            }
            int cb = mh*2 + (q >> 1);
            *(half4v*)(outb + cb*CS + pos*8 + (q & 1)*4) = hv;
        }
    }
}

// ---------------- conv layer L1..L3 (register-pipelined taps) ----------------
// in/out: LDS f16, 4 chunks x rows x 8 halves (chunk cb holds ci 8cb..8cb+7).
// B-frag (lane l): pos = base+(l&15)+tap, ci = (l>>4)*8+j -> one b128 at q*CS+pos*8.
// Tap t+1's 2 A-loads + 3 B-reads prefetch into named regs while tap t's 6 MFMAs
// run (forces the lookahead hipcc declined at VGPR=40; now ~75 <= 85 cap).
template<int K, int DOFF>
__device__ __forceinline__ void conv_layer(
    const _Float16* __restrict__ rec, const float2* __restrict__ bo,
    const _Float16* in, _Float16* outb, int s0, int ntb, int lane)
{
    const int q = lane >> 4, n = lane & 15;
    const _Float16* bbase = in + q*CS + (ntb*16 + n)*8;

    f32x4 acc[3][2];
#pragma unroll
    for (int nt = 0; nt < 3; ++nt)
#pragma unroll
        for (int mh = 0; mh < 2; ++mh) acc[nt][mh] = (f32x4){0.f, 0.f, 0.f, 0.f};

    half8 a0 = *(const half8*)(rec + 0*512 + lane*8);
    half8 a1 = *(const half8*)(rec + 1*512 + lane*8);
    half8 b0 = *(const half8*)(bbase + 0*128);
    half8 b1 = *(const half8*)(bbase + 1*128);
    half8 b2 = *(const half8*)(bbase + 2*128);

#pragma unroll
    for (int tap = 0; tap < K; ++tap) {
        half8 na0, na1, nb0, nb1, nb2;
        if (tap + 1 < K) {
            na0 = *(const half8*)(rec + ((tap+1)*2 + 0)*512 + lane*8);
            na1 = *(const half8*)(rec + ((tap+1)*2 + 1)*512 + lane*8);
            nb0 = *(const half8*)(bbase + 0*128 + (tap+1)*8);
            nb1 = *(const half8*)(bbase + 1*128 + (tap+1)*8);
            nb2 = *(const half8*)(bbase + 2*128 + (tap+1)*8);
        }
        acc[0][0] = __builtin_amdgcn_mfma_f32_16x16x32_f16(a0, b0, acc[0][0], 0, 0, 0);
        acc[0][1] = __builtin_amdgcn_mfma_f32_16x16x32_f16(a1, b0, acc[0][1], 0, 0, 0);
        acc[1][0] = __builtin_amdgcn_mfma_f32_16x16x32_f16(a0, b1, acc[1][0], 0, 0, 0);
        acc[1][1] = __builtin_amdgcn_mfma_f32_16x16x32_f16(a1, b1, acc[1][1], 0, 0, 0);
        acc[2][0] = __builtin_amdgcn_mfma_f32_16x16x32_f16(a0, b2, acc[2][0], 0, 0, 0);
        acc[2][1] = __builtin_amdgcn_mfma_f32_16x16x32_f16(a1, b2, acc[2][1], 0, 0, 0);
        if (tap + 1 < K) { a0 = na0; a1 = na1; b0 = nb0; b1 = nb1; b2 = nb2; }
    }
    conv_epi(acc, bo, outb, s0, DOFF, ntb, q, n);
}

// ---------------- L0 tap-packed: one MFMA pair per n-tile ----------------
// Staged chunk0 = k 0..7, chunk1 = k 8..15 (k = tap*4+ci, k>=12 zero).
// Quads 2,3 broadcast-read chunks 0,1 (A zero for k>=16 -> values irrelevant
// but same-address broadcast keeps it conflict-free and in-bounds).
__device__ __forceinline__ void conv_layer0(
    const _Float16* __restrict__ rec, const float2* __restrict__ bo,
    const _Float16* in, _Float16* outb, int s0, int ntb, int lane)
{
    const int q = lane >> 4, n = lane & 15;
    const _Float16* bbase = in + (q & 1)*CS + (ntb*16 + n)*8;

    half8 a0 = *(const half8*)(rec + 0*512 + lane*8);
    half8 a1 = *(const half8*)(rec + 1*512 + lane*8);

    f32x4 acc[3][2];
#pragma unroll
    for (int nt = 0; nt < 3; ++nt)
#pragma unroll
        for (int mh = 0; mh < 2; ++mh) acc[nt][mh] = (f32x4){0.f, 0.f, 0.f, 0.f};

#pragma unroll
    for (int nt = 0; nt < 3; ++nt) {
        half8 bf = *(const half8*)(bbase + nt*128);
        acc[nt][0] = __builtin_amdgcn_mfma_f32_16x16x32_f16(a0, bf, acc[nt][0], 0, 0, 0);
        acc[nt][1] = __builtin_amdgcn_mfma_f32_16x16x32_f16(a1, bf, acc[nt][1], 0, 0, 0);
    }
    conv_epi(acc, bo, outb, s0, -6, ntb, q, n);
}

// Buffer origins: staged=s0-7 (taps in k), L0out=s0-6, L1out=s0-5, L2out=s0-3, L3out=s0.
// Validity chain (valid final rows 0..179): L3 reads L2out(bufA) rows <=197 (zeros at
// 192..199), L2 reads L1out(bufB) rows <=195 (rows>=192: leftover staged/uninit, finite
// or NaN -> feeds only columns past validity; MFMA columns independent), L1 reads
// L0out(bufA) rows <=193 (zeros), L0 reads staged rows <=191 (<198). Same chain as
// R0/R7 which passed on hardware.
extern "C" __global__ void __launch_bounds__(NTHR, 6)
dnashape_mfma(const float* __restrict__ x, const _Float16* __restrict__ ws,
              const float* __restrict__ fw2, const float* __restrict__ fb2,
              float* __restrict__ out)
{
    __shared__ _Float16 bufA[4*CS];
    __shared__ _Float16 bufB[4*CS];   // 25.7 KB total -> 6 blocks/CU

    const int tid  = threadIdx.x;
    const int tile = blockIdx.x;
    const int s0   = tile * S_TILE;
    const int b    = blockIdx.y;

    // ---- stage tap-packed: row r halves[k=tap*4+ci] = x[ci][s0-7+r+tap]; k>=12 -> 0
    // chunk0 = halves 0..7, chunk1 = halves 8..15 (R5-verified staging pattern).
    {
        const float* xb = x + b*4*SEQ;
        for (int li = tid; li < NROW; li += NTHR) {
            _Float16 h[16];
#pragma unroll
            for (int tap = 0; tap < 3; ++tap) {
                int sg = s0 - 7 + li + tap;
                bool ok = (unsigned)sg < SEQ;
#pragma unroll
                for (int ci = 0; ci < 4; ++ci)
                    h[tap*4 + ci] = (_Float16)(ok ? xb[ci*SEQ + sg] : 0.f);
            }
#pragma unroll
            for (int j = 12; j < 16; ++j) h[j] = (_Float16)0.f;
            *(half8*)(&bufB[0*CS + li*8]) = *(half8*)(h);
            *(half8*)(&bufB[1*CS + li*8]) = *(half8*)(h + 8);
        }
        // Zero bufA halo rows 192..199 (read beyond computed range, written by none).
        if (tid < 32) {
            const half8 z8 = {0,0,0,0,0,0,0,0};
            *(half8*)(&bufA[(tid >> 3)*CS + (192 + (tid & 7))*8]) = z8;
        }
    }
    __syncthreads();

    const int lane = tid & 63;
    const int wv   = uni(tid >> 6);
    const int ntb  = wv * 3;                // wave-uniform n-tile base (3 tiles/wave)
    const float*  fa = (const float*)(ws + BN_HALFOFF);
    const float2* bo = (const float2*)fa;

    conv_layer0             (ws,           bo,      bufB, bufA, s0, ntb, lane);
    __syncthreads();
    conv_layer<3, -5>(ws +  2*512,   bo + 32, bufA, bufB, s0, ntb, lane);
    __syncthreads();
    conv_layer<5, -3>(ws +  8*512,   bo + 64, bufB, bufA, s0, ntb, lane);
    __syncthreads();
    conv_layer<7,  0>(ws + 18*512,   bo + 96, bufA, bufB, s0, ntb, lane);
    __syncthreads();

    // MLP 32 -> 16 (relu) -> 1 (fw1*s3 and fb1' prefolded): one MFMA per n-tile.
    {
        const int q = lane >> 4, n = lane & 15;
        half8 am = *(const half8*)(ws + 32*512 + lane*8);
        float fb1v[4], fw2v[4];
#pragma unroll
        for (int r = 0; r < 4; ++r) { fb1v[r] = fa[256 + q*4 + r]; fw2v[r] = fw2[q*4 + r]; }
        float fb2v = fb2[0];
#pragma unroll
        for (int nt = 0; nt < 3; ++nt) {
            int pos = (ntb + nt)*16 + n;
            half8 bf = *(const half8*)(&bufB[q*CS + pos*8]);
            f32x4 d = {0.f, 0.f, 0.f, 0.f};
            d = __builtin_amdgcn_mfma_f32_16x16x32_f16(am, bf, d, 0, 0, 0);
            float part = 0.f;
#pragma unroll
            for (int r = 0; r < 4; ++r) part += fmaxf(d[r] + fb1v[r], 0.f)*fw2v[r];
            part += __shfl_xor(part, 16, 64);   // reduce across the 4 quads (h-blocks)
            part += __shfl_xor(part, 32, 64);
            if (lane < 16) {
                int g = s0 + pos;
                if (pos < S_TILE && g < SEQ) out[b*SEQ + g] = part + fb2v;
            }
        }
    }
}

extern "C" void kernel_launch(void* const* d_in, const int* in_sizes, int n_in,
                              void* d_out, int out_size, void* d_ws, size_t ws_size,
                              hipStream_t stream) {
    const float* p[29];
    for (int i = 0; i < 29; ++i) p[i] = (const float*)d_in[i];
    _Float16* ws = (_Float16*)d_ws;   // needs 33*1024 + 1088 = 34880 B

    prep_kernel<<<dim3(NREC + 1), 144, 0, stream>>>(
        p[1], p[7], p[13], p[19],
        p[2], p[3], p[4], p[5], p[6],
        p[8], p[9], p[10], p[11], p[12],
        p[14], p[15], p[16], p[17], p[18],
        p[20], p[21], p[22], p[23], p[24],
        p[25], p[26], ws);

    dim3 grid((SEQ + S_TILE - 1) / S_TILE, 128);   // 46 x 128, 1 image per block
    dnashape_mfma<<<grid, NTHR, 0, stream>>>(p[0], (const _Float16*)ws,
                                             p[27], p[28], (float*)d_out);
}

// Round 9
// 169.035 us; speedup vs baseline: 1.0250x; 1.0250x over previous
//
#include <hip/hip_runtime.h>

#define SEQ    8192
#define S_TILE 180            // valid output positions per tile (192 computed - 12 shrink)
#define NROW   198            // staged input rows (192 + halo 6)
#define CS     1608           // chunk stride in halves; holds 201 rows (192 + halo + pad)
#define NTHR   256            // 4 waves, ONE image per block; wave owns 3 n-tiles
#define NREC   33             // A-records: L0:2 (tap-packed), L1:6, L2:10, L3:14, MLP:1
#define BN_HALFOFF (NREC*512) // float area offset (in halves) inside d_ws

typedef __attribute__((ext_vector_type(8))) _Float16 half8;
typedef __attribute__((ext_vector_type(4))) float    f32x4;

__device__ __forceinline__ int uni(int v){ return __builtin_amdgcn_readfirstlane(v); }

// Unrolled (compile-time K) bias fold: sum_ci (sum_tap W[co][ci][tap]) * t_prev[ci].
template<int K>
__device__ __forceinline__ float fold_bias(const float* __restrict__ W, int co,
    const float* __restrict__ gp, const float* __restrict__ bbp,
    const float* __restrict__ rmp, const float* __restrict__ rvp)
{
    float acc = 0.f;
#pragma unroll
    for (int ci = 0; ci < 32; ++ci) {
        float sp = gp[ci] * rsqrtf(rvp[ci] + 1e-5f);
        float tp = bbp[ci] - rmp[ci]*sp;
        float wsum = 0.f;
#pragma unroll
        for (int tap = 0; tap < K; ++tap) wsum += W[(co*32 + ci)*K + tap];
        acc += wsum * tp;
    }
    return acc;
}

// ---------------- prep ----------------
// A-records in the 16x16x32 A-layout: lane l holds A[m][k=(l>>4)*8+j], q=l>>4.
//  rec 0..1  : L0 TAP-PACKED (m = rec*16+(l&15)): k = tap*4+ci (k<12), W0 raw; k>=12 -> 0.
//  rec 2..31 : L1/L2/L3 (tap,mh): m = co = mh*16+(l&15), PERMUTED ci:
//              ci(k=q*8+j) = (j>>2)*16 + q*4 + (j&3)   [matches b128 epilogue pack]
//              value = W[co][ci]*s_prev[ci].
//  rec 32    : MLP: m = h = l&15, same ci perm, value = fw1[h][ci]*s3[ci].
// Float area: [4][32]{bias', oob_const} then fb1'[16]. Stored activations are
// r = relu(z + bias'); seq-OOB positions store -t/s so folded math sees 0.
extern "C" __global__ void prep_kernel(
    const float* w0, const float* w1, const float* w2, const float* w3,
    const float* b0, const float* g0, const float* bb0, const float* rm0, const float* rv0,
    const float* b1, const float* g1, const float* bb1, const float* rm1, const float* rv1,
    const float* b2, const float* g2, const float* bb2, const float* rm2, const float* rv2,
    const float* b3, const float* g3, const float* bb3, const float* rm3, const float* rv3,
    const float* fw1, const float* fb1, _Float16* ws)
{
    const int tid = threadIdx.x;
    const int rec = blockIdx.x;
    if (rec < NREC) {
        if (tid < 64) {
            const int lane = tid;
            const int q = lane >> 4;
            half8 h;
            if (rec < 2) {
                // L0 tap-packed: co = rec*16 + (lane&15), k = q*8+j (R8-verified)
                int co = rec*16 + (lane & 15);
#pragma unroll
                for (int j = 0; j < 8; ++j) {
                    int k = q*8 + j;
                    float wv = (k < 12) ? w0[(co*4 + (k & 3))*3 + (k >> 2)] : 0.0f;
                    h[j] = (_Float16)wv;
                }
            } else {
                const float* W; const float *gp, *rvp; int K, r2;
                if      (rec < 8)  { W = w1;  K = 3; r2 = rec - 2;  gp = g0; rvp = rv0; }
                else if (rec < 18) { W = w2;  K = 5; r2 = rec - 8;  gp = g1; rvp = rv1; }
                else if (rec < 32) { W = w3;  K = 7; r2 = rec - 18; gp = g2; rvp = rv2; }
                else               { W = fw1; K = 1; r2 = 0;        gp = g3; rvp = rv3; }
                int tap = r2 >> 1, mh = r2 & 1;
                int co  = mh*16 + (lane & 15);   // rec 32: mh=0 -> co = h
#pragma unroll
                for (int j = 0; j < 8; ++j) {
                    int ci = ((j >> 2) << 4) + q*4 + (j & 3);   // b128-pack perm
                    float wv = W[(co*32 + ci)*K + tap];
                    wv *= gp[ci] * rsqrtf(rvp[ci] + 1e-5f);     // s_prev
                    h[j] = (_Float16)wv;
                }
            }
            *(half8*)(ws + rec*512 + lane*8) = h;
        }
    } else {
        float* fa = (float*)(ws + BN_HALFOFF);
        if (tid < 128) {
            int l = tid >> 5, co = tid & 31;
            const float *g, *bb, *rm, *rv, *bi;
            if      (l == 0) { g=g0; bb=bb0; rm=rm0; rv=rv0; bi=b0; }
            else if (l == 1) { g=g1; bb=bb1; rm=rm1; rv=rv1; bi=b1; }
            else if (l == 2) { g=g2; bb=bb2; rm=rm2; rv=rv2; bi=b2; }
            else             { g=g3; bb=bb3; rm=rm3; rv=rv3; bi=b3; }
            float s = g[co] * rsqrtf(rv[co] + 1e-5f);
            float t = bb[co] - rm[co]*s;
            float bias = bi[co];
            if      (l == 1) bias += fold_bias<3>(w1, co, g0, bb0, rm0, rv0);
            else if (l == 2) bias += fold_bias<5>(w2, co, g1, bb1, rm1, rv1);
            else if (l == 3) bias += fold_bias<7>(w3, co, g2, bb2, rm2, rv2);
            fa[(l*32 + co)*2 + 0] = bias;
            fa[(l*32 + co)*2 + 1] = -t / s;    // stored value at seq-OOB output positions
        } else if (tid < 144) {
            int hh = tid - 128;
            float acc = fb1[hh];
#pragma unroll
            for (int c = 0; c < 32; ++c) {
                float s3 = g3[c] * rsqrtf(rv3[c] + 1e-5f);
                float t3 = bb3[c] - rm3[c]*s3;
                acc += fw1[hh*32 + c] * t3;
            }
            fa[256 + hh] = acc;                // fb1'
        }
    }
}

// ---------------- conv layer L1..L2 (b128 epilogue, bias-in-acc) ----------------
// in/out: LDS f16, 4 chunks x rows x 8 halves. B-frag (lane q,n): b128 at
// q*CS + (pos)*8 -> storage half j holds ci = (j>>2)*16 + q*4 + (j&3) (perm'd
// A-records pair it). Epilogue: lane packs [mh0 r0..3 | mh1 r0..3] -> ONE b128
// at chunk q, row pos (16-lane phase groups walk ascending contiguous 16B).
template<int K, int DOFF>
__device__ __forceinline__ void conv_layer(
    const _Float16* __restrict__ rec, const float2* __restrict__ bo,
    const _Float16* in, _Float16* outb, int s0, int ntb, int lane)
{
    const int q = lane >> 4, n = lane & 15;
    const _Float16* bbase = in + q*CS + (ntb*16 + n)*8;

    float oobc[8];
    f32x4 acc[3][2];
    {
        float bias[8];
#pragma unroll
        for (int i = 0; i < 8; ++i) {
            float2 p = bo[(i >> 2)*16 + q*4 + (i & 3)];
            bias[i] = p.x; oobc[i] = p.y;
        }
#pragma unroll
        for (int nt = 0; nt < 3; ++nt)
#pragma unroll
            for (int mh = 0; mh < 2; ++mh)
                acc[nt][mh] = (f32x4){bias[mh*4+0], bias[mh*4+1], bias[mh*4+2], bias[mh*4+3]};
    }

#pragma unroll
    for (int tap = 0; tap < K; ++tap) {
        half8 a0 = *(const half8*)(rec + (tap*2 + 0)*512 + lane*8);
        half8 a1 = *(const half8*)(rec + (tap*2 + 1)*512 + lane*8);
#pragma unroll
        for (int nt = 0; nt < 3; ++nt) {
            half8 bf = *(const half8*)(bbase + nt*128 + tap*8);
            acc[nt][0] = __builtin_amdgcn_mfma_f32_16x16x32_f16(a0, bf, acc[nt][0], 0, 0, 0);
            acc[nt][1] = __builtin_amdgcn_mfma_f32_16x16x32_f16(a1, bf, acc[nt][1], 0, 0, 0);
        }
    }

#pragma unroll
    for (int nt = 0; nt < 3; ++nt) {
        int pos = (ntb + nt)*16 + n;
        bool oob = (unsigned)(s0 + DOFF + pos) >= SEQ;
        half8 hv;
#pragma unroll
        for (int mh = 0; mh < 2; ++mh)
#pragma unroll
            for (int r = 0; r < 4; ++r) {
                float v = fmaxf(acc[nt][mh][r], 0.0f);
                if (oob) v = oobc[mh*4 + r];
                hv[mh*4 + r] = (_Float16)v;
            }
        *(half8*)(outb + q*CS + pos*8) = hv;
    }
}

// ---------------- L0 tap-packed (R8-verified B path, b128 epilogue) ----------------
__device__ __forceinline__ void conv_layer0(
    const _Float16* __restrict__ rec, const float2* __restrict__ bo,
    const _Float16* in, _Float16* outb, int s0, int ntb, int lane)
{
    const int q = lane >> 4, n = lane & 15;
    const _Float16* bbase = in + (q & 1)*CS + (ntb*16 + n)*8;

    float oobc[8];
    f32x4 acc[3][2];
    {
        float bias[8];
#pragma unroll
        for (int i = 0; i < 8; ++i) {
            float2 p = bo[(i >> 2)*16 + q*4 + (i & 3)];
            bias[i] = p.x; oobc[i] = p.y;
        }
#pragma unroll
        for (int nt = 0; nt < 3; ++nt)
#pragma unroll
            for (int mh = 0; mh < 2; ++mh)
                acc[nt][mh] = (f32x4){bias[mh*4+0], bias[mh*4+1], bias[mh*4+2], bias[mh*4+3]};
    }

    half8 a0 = *(const half8*)(rec + 0*512 + lane*8);
    half8 a1 = *(const half8*)(rec + 1*512 + lane*8);
#pragma unroll
    for (int nt = 0; nt < 3; ++nt) {
        half8 bf = *(const half8*)(bbase + nt*128);
        acc[nt][0] = __builtin_amdgcn_mfma_f32_16x16x32_f16(a0, bf, acc[nt][0], 0, 0, 0);
        acc[nt][1] = __builtin_amdgcn_mfma_f32_16x16x32_f16(a1, bf, acc[nt][1], 0, 0, 0);
    }

#pragma unroll
    for (int nt = 0; nt < 3; ++nt) {
        int pos = (ntb + nt)*16 + n;
        bool oob = (unsigned)(s0 - 6 + pos) >= SEQ;
        half8 hv;
#pragma unroll
        for (int mh = 0; mh < 2; ++mh)
#pragma unroll
            for (int r = 0; r < 4; ++r) {
                float v = fmaxf(acc[nt][mh][r], 0.0f);
                if (oob) v = oobc[mh*4 + r];
                hv[mh*4 + r] = (_Float16)v;
            }
        *(half8*)(outb + q*CS + pos*8) = hv;
    }
}

// Buffer origins: staged=s0-7 (taps in k), L0out=s0-6, L1out=s0-5, L2out=s0-3, L3=s0.
// Validity chain (valid final rows 0..179): L3 reads L2out(bufA) rows <=197 (zeros at
// 192..199), L2 reads L1out(bufB) rows <=195 (rows>=192: leftover staged/finite data,
// feeds only columns past validity; MFMA columns independent), L1 reads L0out(bufA)
// rows <=193 (zeros), L0 reads staged rows <=191 (<198). Same chain as R0/R7/R8.
extern "C" __global__ void __launch_bounds__(NTHR, 6)
dnashape_mfma(const float* __restrict__ x, const _Float16* __restrict__ ws,
              const float* __restrict__ fw2, const float* __restrict__ fb2,
              float* __restrict__ out)
{
    __shared__ _Float16 bufA[4*CS];
    __shared__ _Float16 bufB[4*CS];   // 25.7 KB total -> 6 blocks/CU

    const int tid  = threadIdx.x;
    const int tile = blockIdx.x;
    const int s0   = tile * S_TILE;
    const int b    = blockIdx.y;

    // ---- stage tap-packed: row r halves[k=tap*4+ci] = x[ci][s0-7+r+tap]; k>=12 -> 0
    {
        const float* xb = x + b*4*SEQ;
        for (int li = tid; li < NROW; li += NTHR) {
            _Float16 h[16];
#pragma unroll
            for (int tap = 0; tap < 3; ++tap) {
                int sg = s0 - 7 + li + tap;
                bool ok = (unsigned)sg < SEQ;
#pragma unroll
                for (int ci = 0; ci < 4; ++ci)
                    h[tap*4 + ci] = (_Float16)(ok ? xb[ci*SEQ + sg] : 0.f);
            }
#pragma unroll
            for (int j = 12; j < 16; ++j) h[j] = (_Float16)0.f;
            *(half8*)(&bufB[0*CS + li*8]) = *(half8*)(h);
            *(half8*)(&bufB[1*CS + li*8]) = *(half8*)(h + 8);
        }
        // Zero bufA halo rows 192..199 (read beyond computed range, written by none).
        if (tid < 32) {
            const half8 z8 = {0,0,0,0,0,0,0,0};
            *(half8*)(&bufA[(tid >> 3)*CS + (192 + (tid & 7))*8]) = z8;
        }
    }
    __syncthreads();

    const int lane = tid & 63;
    const int wv   = uni(tid >> 6);
    const int ntb  = wv * 3;                // wave-uniform n-tile base (3 tiles/wave)
    const float*  fa = (const float*)(ws + BN_HALFOFF);
    const float2* bo = (const float2*)fa;

    conv_layer0      (ws,          bo,      bufB, bufA, s0, ntb, lane);
    __syncthreads();
    conv_layer<3, -5>(ws +  2*512, bo + 32, bufA, bufB, s0, ntb, lane);
    __syncthreads();
    conv_layer<5, -3>(ws +  8*512, bo + 64, bufB, bufA, s0, ntb, lane);
    __syncthreads();

    // ---- L3 fused with MLP, fully in-register (no store, no 4th barrier, no read):
    // packed epilogue half8 [mh0 r0..3 | mh1 r0..3] IS the MLP B-frag (k=q*8+j,
    // col=n) under the perm'd rec-32 A-record. No oob handling: discarded MFMA
    // columns are independent and all inputs finite.
    {
        const int q = lane >> 4, n = lane & 15;
        const _Float16* rec3 = ws + 18*512;
        const _Float16* bbase = bufA + q*CS + (ntb*16 + n)*8;
        const float2* bo3 = bo + 96;

        f32x4 acc[3][2];
        {
            float bias[8];
#pragma unroll
            for (int i = 0; i < 8; ++i)
                bias[i] = bo3[(i >> 2)*16 + q*4 + (i & 3)].x;
#pragma unroll
            for (int nt = 0; nt < 3; ++nt)
#pragma unroll
                for (int mh = 0; mh < 2; ++mh)
                    acc[nt][mh] = (f32x4){bias[mh*4+0], bias[mh*4+1], bias[mh*4+2], bias[mh*4+3]};
        }

#pragma unroll
        for (int tap = 0; tap < 7; ++tap) {
            half8 a0 = *(const half8*)(rec3 + (tap*2 + 0)*512 + lane*8);
            half8 a1 = *(const half8*)(rec3 + (tap*2 + 1)*512 + lane*8);
#pragma unroll
            for (int nt = 0; nt < 3; ++nt) {
                half8 bf = *(const half8*)(bbase + nt*128 + tap*8);
                acc[nt][0] = __builtin_amdgcn_mfma_f32_16x16x32_f16(a0, bf, acc[nt][0], 0, 0, 0);
                acc[nt][1] = __builtin_amdgcn_mfma_f32_16x16x32_f16(a1, bf, acc[nt][1], 0, 0, 0);
            }
        }

        half8 am = *(const half8*)(ws + 32*512 + lane*8);
        float fb1v[4], fw2v[4];
#pragma unroll
        for (int r = 0; r < 4; ++r) { fb1v[r] = fa[256 + q*4 + r]; fw2v[r] = fw2[q*4 + r]; }
        float fb2v = fb2[0];

#pragma unroll
        for (int nt = 0; nt < 3; ++nt) {
            int pos = (ntb + nt)*16 + n;
            half8 hv;
#pragma unroll
            for (int mh = 0; mh < 2; ++mh)
#pragma unroll
                for (int r = 0; r < 4; ++r)
                    hv[mh*4 + r] = (_Float16)fmaxf(acc[nt][mh][r], 0.0f);
            f32x4 d = {0.f, 0.f, 0.f, 0.f};
            d = __builtin_amdgcn_mfma_f32_16x16x32_f16(am, hv, d, 0, 0, 0);
            float part = 0.f;
#pragma unroll
            for (int r = 0; r < 4; ++r) part += fmaxf(d[r] + fb1v[r], 0.f)*fw2v[r];
            part += __shfl_xor(part, 16, 64);   // reduce across the 4 quads (h-blocks)
            part += __shfl_xor(part, 32, 64);
            if (lane < 16) {
                int g = s0 + pos;
                if (pos < S_TILE && g < SEQ) out[b*SEQ + g] = part + fb2v;
            }
        }
    }
}

extern "C" void kernel_launch(void* const* d_in, const int* in_sizes, int n_in,
                              void* d_out, int out_size, void* d_ws, size_t ws_size,
                              hipStream_t stream) {
    const float* p[29];
    for (int i = 0; i < 29; ++i) p[i] = (const float*)d_in[i];
    _Float16* ws = (_Float16*)d_ws;   // needs 33*1024 + 1088 = 34880 B

    prep_kernel<<<dim3(NREC + 1), 144, 0, stream>>>(
        p[1], p[7], p[13], p[19],
        p[2], p[3], p[4], p[5], p[6],
        p[8], p[9], p[10], p[11], p[12],
        p[14], p[15], p[16], p[17], p[18],
        p[20], p[21], p[22], p[23], p[24],
        p[25], p[26], ws);

    dim3 grid((SEQ + S_TILE - 1) / S_TILE, 128);   // 46 x 128, 1 image per block
    dnashape_mfma<<<grid, NTHR, 0, stream>>>(p[0], (const _Float16*)ws,
                                             p[27], p[28], (float*)d_out);
}